// Round 1
// baseline (2229.337 us; speedup 1.0000x reference)
//
#include <hip/hip_runtime.h>
#include <math.h>

#define NPTS 2048
#define NB 16
#define KNN 20

__device__ __forceinline__ float lrelu(float v) { return fmaxf(v, 0.2f * v); }

// ---- transpose x [B,N,3] -> h0 [B,3,N]
__global__ void transpose_kernel(const float* __restrict__ x, float* __restrict__ h0) {
    int t = blockIdx.x * blockDim.x + threadIdx.x;   // b*N+n
    if (t >= NB * NPTS) return;
    int b = t / NPTS, n = t % NPTS;
    const float* src = x + (size_t)t * 3;
    float* dst = h0 + (size_t)b * 3 * NPTS + n;
    dst[0]        = src[0];
    dst[NPTS]     = src[1];
    dst[2 * NPTS] = src[2];
}

// ---- sq[b,n] = sum_c in[b,c,n]^2
__global__ void sq_kernel(const float* __restrict__ in, long bstride, int C,
                          float* __restrict__ sq) {
    int t = blockIdx.x * blockDim.x + threadIdx.x;
    if (t >= NB * NPTS) return;
    int b = t / NPTS, n = t % NPTS;
    const float* p = in + (size_t)b * bstride + n;
    float s = 0.f;
    for (int c = 0; c < C; ++c) {
        float v = p[(size_t)c * NPTS];
        s = fmaf(v, v, s);
    }
    sq[t] = s;
}

// ---- kNN: 4 query rows per block; score[m] = 2*inner(n,m) - sq[m]
// phase2: every thread accumulates all 4 rows for its 8 m's (block reads x[b] once)
// phase3: wave w owns row w; 32 vals/lane in regs; 20 shuffle-argmax rounds
template<int C>
__global__ __launch_bounds__(256) void knn_kernel(const float* __restrict__ xin, long bstride,
                                                  const float* __restrict__ sq,
                                                  int* __restrict__ idx) {
    __shared__ __align__(16) float xi4[C][4];   // [c][r]
    __shared__ float dist[4][NPTS];
    int b = blockIdx.y;
    int n0 = blockIdx.x * 4;
    int tid = threadIdx.x;
    const float* xb = xin + (size_t)b * bstride;

    for (int e = tid; e < 4 * C; e += 256) {
        int r = e & 3, c = e >> 2;
        xi4[c][r] = xb[(size_t)c * NPTS + n0 + r];
    }
    __syncthreads();

    float acc[4][8];
#pragma unroll
    for (int r = 0; r < 4; ++r)
#pragma unroll
        for (int u = 0; u < 8; ++u) acc[r][u] = 0.f;

#pragma unroll 4
    for (int c = 0; c < C; ++c) {
        float4 wv = *reinterpret_cast<const float4*>(&xi4[c][0]);
        const float* row = xb + (size_t)c * NPTS;
#pragma unroll
        for (int u = 0; u < 8; ++u) {
            float v = row[tid + 256 * u];
            acc[0][u] = fmaf(wv.x, v, acc[0][u]);
            acc[1][u] = fmaf(wv.y, v, acc[1][u]);
            acc[2][u] = fmaf(wv.z, v, acc[2][u]);
            acc[3][u] = fmaf(wv.w, v, acc[3][u]);
        }
    }
#pragma unroll
    for (int u = 0; u < 8; ++u) {
        float sv = sq[b * NPTS + tid + 256 * u];
#pragma unroll
        for (int r = 0; r < 4; ++r)
            dist[r][tid + 256 * u] = 2.f * acc[r][u] - sv;
    }
    __syncthreads();

    int w = tid >> 6;        // row this wave owns
    int lane = tid & 63;
    float v[32];
#pragma unroll
    for (int u = 0; u < 32; ++u) v[u] = dist[w][lane + 64 * u];

    int* out = idx + ((size_t)b * NPTS + n0 + w) * KNN;

    float lv = v[0]; int lm = 0;
#pragma unroll
    for (int u = 1; u < 32; ++u) { if (v[u] > lv) { lv = v[u]; lm = u; } }

    for (int j = 0; j < KNN; ++j) {
        float bv = lv; int bm = lane + 64 * lm;
#pragma unroll
        for (int off = 32; off > 0; off >>= 1) {
            float ov = __shfl_down(bv, off, 64);
            int   om = __shfl_down(bm, off, 64);
            if (ov > bv || (ov == bv && om < bm)) { bv = ov; bm = om; }
        }
        bm = __shfl(bm, 0, 64);
        if (lane == 0) out[j] = bm;
        if ((bm & 63) == lane) {   // winner lane: mark + recompute local max
            int u = bm >> 6;
#pragma unroll
            for (int q = 0; q < 32; ++q) if (q == u) v[q] = -INFINITY;
            lv = v[0]; lm = 0;
#pragma unroll
            for (int q = 1; q < 32; ++q) { if (v[q] > lv) { lv = v[q]; lm = q; } }
        }
    }
}

// ---- Wa[c][o] = W[o][c]; Wd[c][o] = W[o][C+c] - W[o][c]
__global__ void prep_w_kernel(const float* __restrict__ W, int C, int O,
                              float* __restrict__ Wa, float* __restrict__ Wd) {
    int t = blockIdx.x * blockDim.x + threadIdx.x;
    if (t >= C * O) return;
    int c = t / O, o = t % O;
    float a = W[o * 2 * C + c];
    float d = W[o * 2 * C + C + c] - a;
    Wa[c * O + o] = a;
    Wd[c * O + o] = d;
}

// ---- y[b,o,m] = Wa@x_m ; base[b,off+o,n] = Wd@x_n + bias (written into feat slice)
__global__ __launch_bounds__(256) void edge_mm_kernel(const float* __restrict__ xin, long bstride,
                                                      int C, int O,
                                                      const float* __restrict__ Wa,
                                                      const float* __restrict__ Wd,
                                                      const float* __restrict__ bias,
                                                      float* __restrict__ y,
                                                      float* __restrict__ base, long base_bstride) {
    int m = blockIdx.x * 256 + threadIdx.x;
    int ngrp = O >> 3;
    int og = blockIdx.y % ngrp, b = blockIdx.y / ngrp;
    int o0 = og * 8;
    const float* xb = xin + (size_t)b * bstride + m;
    float a1[8], a2[8];
#pragma unroll
    for (int i = 0; i < 8; ++i) { a1[i] = 0.f; a2[i] = 0.f; }
#pragma unroll 2
    for (int c = 0; c < C; ++c) {
        float h = xb[(size_t)c * NPTS];
        const float* wa = Wa + c * O + o0;
        const float* wd = Wd + c * O + o0;
#pragma unroll
        for (int i = 0; i < 8; ++i) {
            a1[i] = fmaf(wa[i], h, a1[i]);
            a2[i] = fmaf(wd[i], h, a2[i]);
        }
    }
#pragma unroll
    for (int i = 0; i < 8; ++i) {
        y[((size_t)b * O + o0 + i) * NPTS + m] = a1[i];
        base[(size_t)b * base_bstride + (size_t)(o0 + i) * NPTS + m] = a2[i] + bias[o0 + i];
    }
}

// ---- feat[b,off+o,n] = lrelu( max_j y[b,o,idx[b,n,j]] + base ) ; in-place on feat slice
__global__ __launch_bounds__(256) void gather_max_kernel(const float* __restrict__ y, int O,
                                                         const int* __restrict__ idx,
                                                         float* __restrict__ feat_slice,
                                                         long bstride) {
    __shared__ float yrow[NPTS];
    int o = blockIdx.x, b = blockIdx.y;
    const float* ysrc = y + ((size_t)b * O + o) * NPTS;
    for (int m = threadIdx.x; m < NPTS; m += 256) yrow[m] = ysrc[m];
    __syncthreads();
    float* fs = feat_slice + (size_t)b * bstride + (size_t)o * NPTS;
    const int* ib = idx + (size_t)b * NPTS * KNN;
    for (int s = 0; s < 8; ++s) {
        int n = threadIdx.x + 256 * s;
        const int* ip = ib + n * KNN;
        float mx = -INFINITY;
#pragma unroll
        for (int j = 0; j < KNN; ++j) mx = fmaxf(mx, yrow[ip[j]]);
        fs[n] = lrelu(mx + fs[n]);
    }
}

// ---- final GEMM (1024x512 @ 512x2048 per batch) with running-max-over-n epilogue
__global__ __launch_bounds__(256) void final_gemm_kernel(const float* __restrict__ feat,
                                                         const float* __restrict__ Wf,
                                                         float* __restrict__ pmax) {
    __shared__ __align__(16) float Ws[32][65];
    __shared__ __align__(16) float Fs[32][128];
    int nt = blockIdx.x, ot = blockIdx.y, b = blockIdx.z;
    int o0 = ot * 64, n0 = nt * 128;
    int tid = threadIdx.x;
    int tx = tid & 15, ty = tid >> 4;
    float acc[4][8];
#pragma unroll
    for (int i = 0; i < 4; ++i)
#pragma unroll
        for (int j = 0; j < 8; ++j) acc[i][j] = 0.f;

    for (int c0 = 0; c0 < 512; c0 += 32) {
        // Ws: 64 o x 32 c (transposed store)
        for (int e = tid; e < 512; e += 256) {
            int ol = e >> 3, cq = e & 7;
            float4 vv = *reinterpret_cast<const float4*>(Wf + (size_t)(o0 + ol) * 512 + c0 + cq * 4);
            Ws[cq * 4 + 0][ol] = vv.x;
            Ws[cq * 4 + 1][ol] = vv.y;
            Ws[cq * 4 + 2][ol] = vv.z;
            Ws[cq * 4 + 3][ol] = vv.w;
        }
        // Fs: 32 c x 128 n
        for (int e = tid; e < 1024; e += 256) {
            int cl = e >> 5, q = e & 31;
            float4 vv = *reinterpret_cast<const float4*>(
                feat + (size_t)b * 512 * NPTS + (size_t)(c0 + cl) * NPTS + n0 + q * 4);
            *reinterpret_cast<float4*>(&Fs[cl][q * 4]) = vv;
        }
        __syncthreads();
#pragma unroll 8
        for (int cc = 0; cc < 32; ++cc) {
            float wv[4], fv[8];
#pragma unroll
            for (int i = 0; i < 4; ++i) wv[i] = Ws[cc][ty + 16 * i];
#pragma unroll
            for (int j = 0; j < 8; ++j) fv[j] = Fs[cc][tx + 16 * j];
#pragma unroll
            for (int i = 0; i < 4; ++i)
#pragma unroll
                for (int j = 0; j < 8; ++j)
                    acc[i][j] = fmaf(wv[i], fv[j], acc[i][j]);
        }
        __syncthreads();
    }
#pragma unroll
    for (int i = 0; i < 4; ++i) {
        float m = acc[i][0];
#pragma unroll
        for (int j = 1; j < 8; ++j) m = fmaxf(m, acc[i][j]);
#pragma unroll
        for (int off = 8; off > 0; off >>= 1) m = fmaxf(m, __shfl_down(m, off, 16));
        if (tx == 0) pmax[((size_t)b * 1024 + o0 + ty + 16 * i) * 16 + nt] = m;
    }
}

__global__ void final_reduce_kernel(const float* __restrict__ pmax,
                                    const float* __restrict__ bf,
                                    float* __restrict__ out) {
    int t = blockIdx.x * blockDim.x + threadIdx.x;   // b*1024+o
    if (t >= NB * 1024) return;
    const float* p = pmax + (size_t)t * 16;
    float m = p[0];
#pragma unroll
    for (int i = 1; i < 16; ++i) m = fmaxf(m, p[i]);
    out[t] = lrelu(m + bf[t & 1023]);
}

extern "C" void kernel_launch(void* const* d_in, const int* in_sizes, int n_in,
                              void* d_out, int out_size, void* d_ws, size_t ws_size,
                              hipStream_t stream) {
    const float* x  = (const float*)d_in[0];
    const float* W[4]  = {(const float*)d_in[1], (const float*)d_in[3],
                          (const float*)d_in[5], (const float*)d_in[7]};
    const float* bb[4] = {(const float*)d_in[2], (const float*)d_in[4],
                          (const float*)d_in[6], (const float*)d_in[8]};
    const float* Wf = (const float*)d_in[9];
    const float* bf = (const float*)d_in[10];
    float* out = (float*)d_out;

    float* ws   = (float*)d_ws;
    float* h0   = ws;                       // B*3*N      = 98304
    float* sq   = h0 + 98304;               // B*N        = 32768
    int*   idx  = (int*)(sq + 32768);       // B*N*20     = 655360
    float* y    = (float*)(idx + 655360);   // B*256*N    = 8388608
    float* feat = y + 8388608;              // B*512*N    = 16777216
    float* pmax = feat + 16777216;          // B*1024*16  = 262144
    float* Wa   = pmax + 262144;            // 128*256    = 32768
    float* Wd   = Wa + 32768;               // 128*256    = 32768

    transpose_kernel<<<128, 256, 0, stream>>>(x, h0);

    const int  Cs[4]   = {3, 64, 64, 128};
    const int  Os[4]   = {64, 64, 128, 256};
    const int  offs[4] = {0, 64, 128, 256};

    for (int l = 0; l < 4; ++l) {
        const float* in = (l == 0) ? h0 : feat + (size_t)offs[l - 1] * NPTS;
        long bstr = (l == 0) ? (long)3 * NPTS : (long)512 * NPTS;
        int C = Cs[l], O = Os[l];

        sq_kernel<<<128, 256, 0, stream>>>(in, bstr, C, sq);

        dim3 kg(NPTS / 4, NB);
        if (C == 3)       knn_kernel<3>  <<<kg, 256, 0, stream>>>(in, bstr, sq, idx);
        else if (C == 64) knn_kernel<64> <<<kg, 256, 0, stream>>>(in, bstr, sq, idx);
        else              knn_kernel<128><<<kg, 256, 0, stream>>>(in, bstr, sq, idx);

        prep_w_kernel<<<(C * O + 255) / 256, 256, 0, stream>>>(W[l], C, O, Wa, Wd);

        float* fslice = feat + (size_t)offs[l] * NPTS;
        edge_mm_kernel<<<dim3(NPTS / 256, NB * (O >> 3)), 256, 0, stream>>>(
            in, bstr, C, O, Wa, Wd, bb[l], y, fslice, (long)512 * NPTS);

        gather_max_kernel<<<dim3(O, NB), 256, 0, stream>>>(y, O, idx, fslice, (long)512 * NPTS);
    }

    final_gemm_kernel<<<dim3(16, 16, 16), 256, 0, stream>>>(feat, Wf, pmax);
    final_reduce_kernel<<<64, 256, 0, stream>>>(pmax, bf, out);
}

// Round 2
// 1821.271 us; speedup vs baseline: 1.2241x; 1.2241x over previous
//
#include <hip/hip_runtime.h>
#include <hip/hip_bf16.h>
#include <math.h>

#define NPTS 2048
#define NB 16
#define KNN 20

typedef __attribute__((ext_vector_type(8))) short bf16x8;
typedef __attribute__((ext_vector_type(4))) float f32x4;

__device__ __forceinline__ float lrelu(float v) { return fmaxf(v, 0.2f * v); }

// split two floats into packed bf16 hi pair + packed bf16 lo (residual) pair
__device__ __forceinline__ void split2(float a, float b, unsigned& hp, unsigned& lp) {
    float2 f2; f2.x = a; f2.y = b;
    __hip_bfloat162 h2 = __float22bfloat162_rn(f2);
    unsigned hb; __builtin_memcpy(&hb, &h2, 4);
    float la = a - __uint_as_float(hb << 16);
    float lb = b - __uint_as_float(hb & 0xFFFF0000u);
    float2 l2; l2.x = la; l2.y = lb;
    __hip_bfloat162 k2 = __float22bfloat162_rn(l2);
    unsigned lb2; __builtin_memcpy(&lb2, &k2, 4);
    hp = hb; lp = lb2;
}

// ---- transpose x [B,N,3] -> h0 [B,3,N]
__global__ void transpose_kernel(const float* __restrict__ x, float* __restrict__ h0) {
    int t = blockIdx.x * blockDim.x + threadIdx.x;   // b*N+n
    if (t >= NB * NPTS) return;
    int b = t / NPTS, n = t % NPTS;
    const float* src = x + (size_t)t * 3;
    float* dst = h0 + (size_t)b * 3 * NPTS + n;
    dst[0]        = src[0];
    dst[NPTS]     = src[1];
    dst[2 * NPTS] = src[2];
}

// ---- sq[b,n] = sum_c in[b,c,n]^2
__global__ void sq_kernel(const float* __restrict__ in, long bstride, int C,
                          float* __restrict__ sq) {
    int t = blockIdx.x * blockDim.x + threadIdx.x;
    if (t >= NB * NPTS) return;
    int b = t / NPTS, n = t % NPTS;
    const float* p = in + (size_t)b * bstride + n;
    float s = 0.f;
    for (int c = 0; c < C; ++c) {
        float v = p[(size_t)c * NPTS];
        s = fmaf(v, v, s);
    }
    sq[t] = s;
}

// ---- kNN: 4 query rows per block; score[m] = 2*inner(n,m) - sq[m]
template<int C>
__global__ __launch_bounds__(256) void knn_kernel(const float* __restrict__ xin, long bstride,
                                                  const float* __restrict__ sq,
                                                  int* __restrict__ idx) {
    __shared__ __align__(16) float xi4[C][4];   // [c][r]
    __shared__ float dist[4][NPTS];
    int b = blockIdx.y;
    int n0 = blockIdx.x * 4;
    int tid = threadIdx.x;
    const float* xb = xin + (size_t)b * bstride;

    for (int e = tid; e < 4 * C; e += 256) {
        int r = e & 3, c = e >> 2;
        xi4[c][r] = xb[(size_t)c * NPTS + n0 + r];
    }
    __syncthreads();

    float acc[4][8];
#pragma unroll
    for (int r = 0; r < 4; ++r)
#pragma unroll
        for (int u = 0; u < 8; ++u) acc[r][u] = 0.f;

#pragma unroll 4
    for (int c = 0; c < C; ++c) {
        float4 wv = *reinterpret_cast<const float4*>(&xi4[c][0]);
        const float* row = xb + (size_t)c * NPTS;
#pragma unroll
        for (int u = 0; u < 8; ++u) {
            float v = row[tid + 256 * u];
            acc[0][u] = fmaf(wv.x, v, acc[0][u]);
            acc[1][u] = fmaf(wv.y, v, acc[1][u]);
            acc[2][u] = fmaf(wv.z, v, acc[2][u]);
            acc[3][u] = fmaf(wv.w, v, acc[3][u]);
        }
    }
#pragma unroll
    for (int u = 0; u < 8; ++u) {
        float sv = sq[b * NPTS + tid + 256 * u];
#pragma unroll
        for (int r = 0; r < 4; ++r)
            dist[r][tid + 256 * u] = 2.f * acc[r][u] - sv;
    }
    __syncthreads();

    int w = tid >> 6;        // row this wave owns
    int lane = tid & 63;
    float v[32];
#pragma unroll
    for (int u = 0; u < 32; ++u) v[u] = dist[w][lane + 64 * u];

    int* out = idx + ((size_t)b * NPTS + n0 + w) * KNN;

    float lv = v[0]; int lm = 0;
#pragma unroll
    for (int u = 1; u < 32; ++u) { if (v[u] > lv) { lv = v[u]; lm = u; } }

    for (int j = 0; j < KNN; ++j) {
        float bv = lv; int bm = lane + 64 * lm;
#pragma unroll
        for (int off = 32; off > 0; off >>= 1) {
            float ov = __shfl_down(bv, off, 64);
            int   om = __shfl_down(bm, off, 64);
            if (ov > bv || (ov == bv && om < bm)) { bv = ov; bm = om; }
        }
        bm = __shfl(bm, 0, 64);
        if (lane == 0) out[j] = bm;
        if ((bm & 63) == lane) {
            int u = bm >> 6;
#pragma unroll
            for (int q = 0; q < 32; ++q) if (q == u) v[q] = -INFINITY;
            lv = v[0]; lm = 0;
#pragma unroll
            for (int q = 1; q < 32; ++q) { if (v[q] > lv) { lv = v[q]; lm = q; } }
        }
    }
}

// ---- Wa[c][o] = W[o][c]; Wd[c][o] = W[o][C+c] - W[o][c]
__global__ void prep_w_kernel(const float* __restrict__ W, int C, int O,
                              float* __restrict__ Wa, float* __restrict__ Wd) {
    int t = blockIdx.x * blockDim.x + threadIdx.x;
    if (t >= C * O) return;
    int c = t / O, o = t % O;
    float a = W[o * 2 * C + c];
    float d = W[o * 2 * C + C + c] - a;
    Wa[c * O + o] = a;
    Wd[c * O + o] = d;
}

// ---- y[b,o,m] = Wa@x_m ; base[b,off+o,n] = Wd@x_n + bias
__global__ __launch_bounds__(256) void edge_mm_kernel(const float* __restrict__ xin, long bstride,
                                                      int C, int O,
                                                      const float* __restrict__ Wa,
                                                      const float* __restrict__ Wd,
                                                      const float* __restrict__ bias,
                                                      float* __restrict__ y,
                                                      float* __restrict__ base, long base_bstride) {
    int m = blockIdx.x * 256 + threadIdx.x;
    int ngrp = O >> 3;
    int og = blockIdx.y % ngrp, b = blockIdx.y / ngrp;
    int o0 = og * 8;
    const float* xb = xin + (size_t)b * bstride + m;
    float a1[8], a2[8];
#pragma unroll
    for (int i = 0; i < 8; ++i) { a1[i] = 0.f; a2[i] = 0.f; }
#pragma unroll 2
    for (int c = 0; c < C; ++c) {
        float h = xb[(size_t)c * NPTS];
        const float* wa = Wa + c * O + o0;
        const float* wd = Wd + c * O + o0;
#pragma unroll
        for (int i = 0; i < 8; ++i) {
            a1[i] = fmaf(wa[i], h, a1[i]);
            a2[i] = fmaf(wd[i], h, a2[i]);
        }
    }
#pragma unroll
    for (int i = 0; i < 8; ++i) {
        y[((size_t)b * O + o0 + i) * NPTS + m] = a1[i];
        base[(size_t)b * base_bstride + (size_t)(o0 + i) * NPTS + m] = a2[i] + bias[o0 + i];
    }
}

// ---- feat[b,off+o,n] = lrelu( max_j y[b,o,idx[b,n,j]] + base )
__global__ __launch_bounds__(256) void gather_max_kernel(const float* __restrict__ y, int O,
                                                         const int* __restrict__ idx,
                                                         float* __restrict__ feat_slice,
                                                         long bstride) {
    __shared__ float yrow[NPTS];
    int o = blockIdx.x, b = blockIdx.y;
    const float* ysrc = y + ((size_t)b * O + o) * NPTS;
    for (int m = threadIdx.x; m < NPTS; m += 256) yrow[m] = ysrc[m];
    __syncthreads();
    float* fs = feat_slice + (size_t)b * bstride + (size_t)o * NPTS;
    const int* ib = idx + (size_t)b * NPTS * KNN;
    for (int s = 0; s < 8; ++s) {
        int n = threadIdx.x + 256 * s;
        const int* ip = ib + n * KNN;
        float mx = -INFINITY;
#pragma unroll
        for (int j = 0; j < KNN; ++j) mx = fmaxf(mx, yrow[ip[j]]);
        fs[n] = lrelu(mx + fs[n]);
    }
}

// ---- split Wf (fp32 [1024][512]) into packed bf16 hi/lo
__global__ void wf_split_kernel(const float* __restrict__ Wf,
                                unsigned* __restrict__ Wfh, unsigned* __restrict__ Wfl) {
    int t = blockIdx.x * 256 + threadIdx.x;   // pair index
    if (t >= 262144) return;
    unsigned h, l;
    split2(Wf[2 * t], Wf[2 * t + 1], h, l);
    Wfh[t] = h; Wfl[t] = l;
}

// ---- final GEMM via bf16 hi/lo split MFMA, with max-over-n epilogue
// block tile: M=128 (o), N=128 (n), K-step 32 (c). 4 waves in 2x2; wave = 64x64.
#define GP 40   // LDS pitch in bf16 elements (+8 pad: 2-way bank aliasing only)
__global__ __launch_bounds__(256) void final_gemm_mfma(
    const float* __restrict__ feat,
    const unsigned short* __restrict__ Wfh,
    const unsigned short* __restrict__ Wfl,
    float* __restrict__ pmax) {
    __shared__ __align__(16) unsigned short Ah[128 * GP];
    __shared__ __align__(16) unsigned short Al[128 * GP];
    __shared__ __align__(16) unsigned short Bh[128 * GP];
    __shared__ __align__(16) unsigned short Bl[128 * GP];

    int ot = blockIdx.x, nt = blockIdx.y, b = blockIdx.z;
    int o0 = ot * 128, n0 = nt * 128;
    int tid = threadIdx.x;
    int lane = tid & 63, w = tid >> 6;
    int wm = w & 1, wn = w >> 1;
    int l15 = lane & 15, q = lane >> 4;

    f32x4 acc[4][4];
#pragma unroll
    for (int mi = 0; mi < 4; ++mi)
#pragma unroll
        for (int ni = 0; ni < 4; ++ni) acc[mi][ni] = (f32x4)0.f;

    const float* fb = feat + (size_t)b * 512 * NPTS;

    // B staging indices: thread covers n = tid&127, k-half kh = tid>>7 (16 k's)
    int bn = tid & 127, kh = tid >> 7;

    for (int c0 = 0; c0 < 512; c0 += 32) {
        // ---- stage A (Wf hi/lo, already bf16): 128 o x 32 k
#pragma unroll
        for (int p = 0; p < 2; ++p) {
            int e = p * 256 + tid;
            int r = e >> 2, qq = e & 3;
            size_t go = (size_t)(o0 + r) * 512 + c0 + qq * 8;
            *(uint4*)&Ah[r * GP + qq * 8] = *(const uint4*)(Wfh + go);
            *(uint4*)&Al[r * GP + qq * 8] = *(const uint4*)(Wfl + go);
        }
        // ---- stage B (feat fp32 -> bf16 hi/lo, transposed to [n][k])
        {
            const float* src = fb + (size_t)(c0 + kh * 16) * NPTS + n0 + bn;
            float v[16];
#pragma unroll
            for (int j = 0; j < 16; ++j) v[j] = src[(size_t)j * NPTS];
            unsigned hw[8], lw[8];
#pragma unroll
            for (int p = 0; p < 8; ++p) split2(v[2 * p], v[2 * p + 1], hw[p], lw[p]);
            unsigned short* bh = &Bh[bn * GP + kh * 16];
            unsigned short* bl = &Bl[bn * GP + kh * 16];
            *(uint4*)(bh)     = make_uint4(hw[0], hw[1], hw[2], hw[3]);
            *(uint4*)(bh + 8) = make_uint4(hw[4], hw[5], hw[6], hw[7]);
            *(uint4*)(bl)     = make_uint4(lw[0], lw[1], lw[2], lw[3]);
            *(uint4*)(bl + 8) = make_uint4(lw[4], lw[5], lw[6], lw[7]);
        }
        __syncthreads();

        bf16x8 bhf[4], blf[4];
#pragma unroll
        for (int ni = 0; ni < 4; ++ni) {
            int row = wn * 64 + ni * 16 + l15;
            bhf[ni] = *(const bf16x8*)&Bh[row * GP + q * 8];
            blf[ni] = *(const bf16x8*)&Bl[row * GP + q * 8];
        }
#pragma unroll
        for (int mi = 0; mi < 4; ++mi) {
            int row = wm * 64 + mi * 16 + l15;
            bf16x8 ah = *(const bf16x8*)&Ah[row * GP + q * 8];
            bf16x8 al = *(const bf16x8*)&Al[row * GP + q * 8];
#pragma unroll
            for (int ni = 0; ni < 4; ++ni) {
                acc[mi][ni] = __builtin_amdgcn_mfma_f32_16x16x32_bf16(ah, bhf[ni], acc[mi][ni], 0, 0, 0);
                acc[mi][ni] = __builtin_amdgcn_mfma_f32_16x16x32_bf16(ah, blf[ni], acc[mi][ni], 0, 0, 0);
                acc[mi][ni] = __builtin_amdgcn_mfma_f32_16x16x32_bf16(al, bhf[ni], acc[mi][ni], 0, 0, 0);
            }
        }
        __syncthreads();
    }

    // ---- epilogue: max over the 64 n columns this wave owns
    int slot = nt * 2 + wn;   // 32 slots total
#pragma unroll
    for (int mi = 0; mi < 4; ++mi) {
        float m4[4];
#pragma unroll
        for (int r = 0; r < 4; ++r) {
            float m = acc[mi][0][r];
            m = fmaxf(m, acc[mi][1][r]);
            m = fmaxf(m, acc[mi][2][r]);
            m = fmaxf(m, acc[mi][3][r]);
            m4[r] = m;
        }
#pragma unroll
        for (int off = 1; off < 16; off <<= 1) {
#pragma unroll
            for (int r = 0; r < 4; ++r)
                m4[r] = fmaxf(m4[r], __shfl_xor(m4[r], off, 16));
        }
        if (l15 == 0) {
            int mbase = o0 + wm * 64 + mi * 16 + q * 4;
#pragma unroll
            for (int r = 0; r < 4; ++r)
                pmax[((size_t)b * 1024 + mbase + r) * 32 + slot] = m4[r];
        }
    }
}

__global__ void final_reduce_kernel(const float* __restrict__ pmax,
                                    const float* __restrict__ bf,
                                    float* __restrict__ out) {
    int t = blockIdx.x * blockDim.x + threadIdx.x;   // b*1024+o
    if (t >= NB * 1024) return;
    const float* p = pmax + (size_t)t * 32;
    float m = p[0];
#pragma unroll
    for (int i = 1; i < 32; ++i) m = fmaxf(m, p[i]);
    out[t] = lrelu(m + bf[t & 1023]);
}

extern "C" void kernel_launch(void* const* d_in, const int* in_sizes, int n_in,
                              void* d_out, int out_size, void* d_ws, size_t ws_size,
                              hipStream_t stream) {
    const float* x  = (const float*)d_in[0];
    const float* W[4]  = {(const float*)d_in[1], (const float*)d_in[3],
                          (const float*)d_in[5], (const float*)d_in[7]};
    const float* bb[4] = {(const float*)d_in[2], (const float*)d_in[4],
                          (const float*)d_in[6], (const float*)d_in[8]};
    const float* Wf = (const float*)d_in[9];
    const float* bf = (const float*)d_in[10];
    float* out = (float*)d_out;

    float* ws   = (float*)d_ws;
    float* h0   = ws;                       // B*3*N      = 98304
    float* sq   = h0 + 98304;               // B*N        = 32768
    int*   idx  = (int*)(sq + 32768);       // B*N*20     = 655360
    float* y    = (float*)(idx + 655360);   // B*256*N    = 8388608 (reused after layers)
    float* feat = y + 8388608;              // B*512*N    = 16777216
    float* Wa   = feat + 16777216 + 262144; // 128*256    = 32768 (same offsets as before)
    float* Wd   = Wa + 32768;               // 128*256    = 32768

    // carved out of the dead y-region after layer 4:
    unsigned* Wfh = (unsigned*)y;                    // 262144 dwords (524288 ushort)
    unsigned* Wfl = (unsigned*)(y + 262144);         // 262144 dwords
    float*    pmax = y + 524288;                     // 16*1024*32 = 524288 floats

    transpose_kernel<<<128, 256, 0, stream>>>(x, h0);

    const int  Cs[4]   = {3, 64, 64, 128};
    const int  Os[4]   = {64, 64, 128, 256};
    const int  offs[4] = {0, 64, 128, 256};

    for (int l = 0; l < 4; ++l) {
        const float* in = (l == 0) ? h0 : feat + (size_t)offs[l - 1] * NPTS;
        long bstr = (l == 0) ? (long)3 * NPTS : (long)512 * NPTS;
        int C = Cs[l], O = Os[l];

        sq_kernel<<<128, 256, 0, stream>>>(in, bstr, C, sq);

        dim3 kg(NPTS / 4, NB);
        if (C == 3)       knn_kernel<3>  <<<kg, 256, 0, stream>>>(in, bstr, sq, idx);
        else if (C == 64) knn_kernel<64> <<<kg, 256, 0, stream>>>(in, bstr, sq, idx);
        else              knn_kernel<128><<<kg, 256, 0, stream>>>(in, bstr, sq, idx);

        prep_w_kernel<<<(C * O + 255) / 256, 256, 0, stream>>>(W[l], C, O, Wa, Wd);

        float* fslice = feat + (size_t)offs[l] * NPTS;
        edge_mm_kernel<<<dim3(NPTS / 256, NB * (O >> 3)), 256, 0, stream>>>(
            in, bstr, C, O, Wa, Wd, bb[l], y, fslice, (long)512 * NPTS);

        gather_max_kernel<<<dim3(O, NB), 256, 0, stream>>>(y, O, idx, fslice, (long)512 * NPTS);
    }

    wf_split_kernel<<<1024, 256, 0, stream>>>(Wf, Wfh, Wfl);
    final_gemm_mfma<<<dim3(8, 16, NB), 256, 0, stream>>>(
        feat, (const unsigned short*)Wfh, (const unsigned short*)Wfl, pmax);
    final_reduce_kernel<<<64, 256, 0, stream>>>(pmax, bf, out);
}